// Round 9
// baseline (205.946 us; speedup 1.0000x reference)
//
#include <hip/hip_runtime.h>
#include <math.h>

#define KDIM 64
#define TDIM 100
#define VDIM 10000
#define NV4  2500            // VDIM / 4
#define BLOCK 512
#define NWAVE (BLOCK / 64)   // 8
#define VPT 5                // ceil(NV4 / BLOCK)
#define CHUNK 5
#define NCHUNK (TDIM / CHUNK)

#define INV1 (1.0f / (1.0f + 1e-6f))
#define INVD (1.0f / (0.005f + 1e-6f))
#define LOGD (-5.2983173665480363f)   // log(0.005f)

// native clang vector type: __builtin_nontemporal_* accepts this, and it has
// identical layout/codegen (global_load_dwordx4) to HIP's float4.
typedef float vf4 __attribute__((ext_vector_type(4)));

// guard: jj < VPT-1 rows are always in range (tid + 3*512 <= 2047 < 2500)
#define INRANGE(jj, idx) ((jj) < VPT - 1 || (idx) < NV4)

__device__ __forceinline__ float wave_red_sum(float v) {
#pragma unroll
    for (int m = 32; m >= 1; m >>= 1) v += __shfl_xor(v, m, 64);
    return v;
}

// barrier that does NOT drain vmcnt: global loads/stores stay in flight.
// lgkmcnt(0) commits our ds_write of the reduction slot before the barrier.
__device__ __forceinline__ void lds_barrier() {
    asm volatile("s_waitcnt lgkmcnt(0)\n\ts_barrier" ::: "memory");
}

// Software pipeline: row t+1's 15 loads are issued after consuming row t and
// BEFORE the reduction barrier + output stores, and are loop-carried in
// M/L/E -> the compiler must keep them in flight across the whole back half
// of the iteration (~full phase of latency cover). bprev in LDS is what
// frees the registers for this.
__global__ __launch_bounds__(BLOCK, 4) void fused_beta_softmax_kl(
    const float* __restrict__ mu_q,   // [K, T, V]
    const float* __restrict__ lsq,    // [K, T, V]
    const float* __restrict__ eps,    // [T, K, V]
    float* __restrict__ out,          // [T, K, V]
    float* __restrict__ kl)           // scalar (pre-zeroed)
{
    __shared__ vf4 bprev[NV4];        // 40 KB: beta of current row, thread-private slots
    __shared__ float red[2][NWAVE];
    __shared__ float kred[NWAVE];

    const int tid = threadIdx.x;
    const int bid = blockIdx.x;
    const int k   = bid / NCHUNK;
    const int c   = bid % NCHUNK;
    const int t0  = c * CHUNK;
    const int tend = t0 + CHUNK;
    const bool epi = (tend < TDIM);   // this block computes KL term of row tend too

    float klacc = 0.0f;
    vf4 M[VPT], L[VPT], E[VPT];       // staging registers, loop-carried

    // ---- prologue: stage row t0 ----
    {
        const size_t po = ((size_t)k * TDIM + t0) * VDIM;
        const size_t eo = ((size_t)t0 * KDIM + k) * VDIM;
        const vf4* m4p = reinterpret_cast<const vf4*>(mu_q + po);
        const vf4* l4p = reinterpret_cast<const vf4*>(lsq + po);
        const vf4* e4p = reinterpret_cast<const vf4*>(eps + eo);
#pragma unroll
        for (int jj = 0; jj < VPT; ++jj) {
            const int idx = tid + jj * BLOCK;
            if (INRANGE(jj, idx)) {
                M[jj] = m4p[idx];
                L[jj] = l4p[idx];
                E[jj] = __builtin_nontemporal_load(&e4p[idx]);
            }
        }
    }

    for (int t = t0; t < tend; ++t) {
        const bool first = (t == 0);
        const bool skip  = (t == t0) && (t0 != 0);   // prev block owns this KL term

        // ---- consume staged row t: beta -> LDS, KL vs old LDS beta, exp-sum ----
        float lsum = 0.0f;
#pragma unroll
        for (int jj = 0; jj < VPT; ++jj) {
            const int idx = tid + jj * BLOCK;
            if (INRANGE(jj, idx)) {
                const vf4 m = M[jj], l = L[jj], e = E[jj];
                // s = exp(l/2); exp(l) = s*s (saves one transcendental)
                const float sx = __expf(0.5f * l.x), sy = __expf(0.5f * l.y),
                            sz = __expf(0.5f * l.z), sw = __expf(0.5f * l.w);
                vf4 b;
                b.x = fmaf(sx, e.x, m.x);
                b.y = fmaf(sy, e.y, m.y);
                b.z = fmaf(sz, e.z, m.z);
                b.w = fmaf(sw, e.w, m.w);
                if (first) {
                    klacc += (sx * sx + m.x * m.x) * INV1 - 1.0f - l.x;
                    klacc += (sy * sy + m.y * m.y) * INV1 - 1.0f - l.y;
                    klacc += (sz * sz + m.z * m.z) * INV1 - 1.0f - l.z;
                    klacc += (sw * sw + m.w * m.w) * INV1 - 1.0f - l.w;
                } else if (!skip) {
                    const vf4 p = bprev[idx];
                    const float dx = m.x - p.x, dy = m.y - p.y,
                                dz = m.z - p.z, dw = m.w - p.w;
                    klacc += (sx * sx + dx * dx) * INVD - 1.0f + LOGD - l.x;
                    klacc += (sy * sy + dy * dy) * INVD - 1.0f + LOGD - l.y;
                    klacc += (sz * sz + dz * dz) * INVD - 1.0f + LOGD - l.z;
                    klacc += (sw * sw + dw * dw) * INVD - 1.0f + LOGD - l.w;
                }
                bprev[idx] = b;
                lsum += __expf(b.x) + __expf(b.y) + __expf(b.z) + __expf(b.w);
            }
        }

        // ---- stage NEXT row now (before barrier + stores): latency cover ----
        if (t + 1 < tend) {
            const size_t po = ((size_t)k * TDIM + (t + 1)) * VDIM;
            const size_t eo = ((size_t)(t + 1) * KDIM + k) * VDIM;
            const vf4* m4p = reinterpret_cast<const vf4*>(mu_q + po);
            const vf4* l4p = reinterpret_cast<const vf4*>(lsq + po);
            const vf4* e4p = reinterpret_cast<const vf4*>(eps + eo);
#pragma unroll
            for (int jj = 0; jj < VPT; ++jj) {
                const int idx = tid + jj * BLOCK;
                if (INRANGE(jj, idx)) {
                    M[jj] = m4p[idx];
                    L[jj] = l4p[idx];
                    E[jj] = __builtin_nontemporal_load(&e4p[idx]);
                }
            }
        } else if (epi) {
            // last row of chunk: stage mu/lsq of row tend for the KL handoff
            const size_t po = ((size_t)k * TDIM + tend) * VDIM;
            const vf4* m4p = reinterpret_cast<const vf4*>(mu_q + po);
            const vf4* l4p = reinterpret_cast<const vf4*>(lsq + po);
#pragma unroll
            for (int jj = 0; jj < VPT; ++jj) {
                const int idx = tid + jj * BLOCK;
                if (INRANGE(jj, idx)) { M[jj] = m4p[idx]; L[jj] = l4p[idx]; }
            }
        }

        // ---- exp-sum block reduction (vmcnt-preserving barrier) ----
        const int slot = t & 1;
        float ws = wave_red_sum(lsum);
        if ((tid & 63) == 0) red[slot][tid >> 6] = ws;
        lds_barrier();
        float rowsum = 0.0f;
#pragma unroll
        for (int w = 0; w < NWAVE; ++w) rowsum += red[slot][w];
        const float invs = 1.0f / rowsum;

        // ---- write softmax = exp(beta) * invs, beta re-read from LDS ----
        vf4* o4p = reinterpret_cast<vf4*>(out + ((size_t)t * KDIM + k) * VDIM);
#pragma unroll
        for (int jj = 0; jj < VPT; ++jj) {
            const int idx = tid + jj * BLOCK;
            if (INRANGE(jj, idx)) {
                const vf4 b = bprev[idx];
                vf4 o;
                o.x = __expf(b.x) * invs;
                o.y = __expf(b.y) * invs;
                o.z = __expf(b.z) * invs;
                o.w = __expf(b.w) * invs;
                __builtin_nontemporal_store(o, &o4p[idx]);
            }
        }
        // bprev slots are thread-private; red double-buffered -> one barrier/row
    }

    // ---- forward-handoff KL for row tend (mu/lsq staged in last iteration) ----
    if (epi) {
#pragma unroll
        for (int jj = 0; jj < VPT; ++jj) {
            const int idx = tid + jj * BLOCK;
            if (INRANGE(jj, idx)) {
                const vf4 m = M[jj], l = L[jj];
                const vf4 p = bprev[idx];
                const float sx = __expf(0.5f * l.x), sy = __expf(0.5f * l.y),
                            sz = __expf(0.5f * l.z), sw = __expf(0.5f * l.w);
                const float dx = m.x - p.x, dy = m.y - p.y,
                            dz = m.z - p.z, dw = m.w - p.w;
                klacc += (sx * sx + dx * dx) * INVD - 1.0f + LOGD - l.x;
                klacc += (sy * sy + dy * dy) * INVD - 1.0f + LOGD - l.y;
                klacc += (sz * sz + dz * dz) * INVD - 1.0f + LOGD - l.z;
                klacc += (sw * sw + dw * dw) * INVD - 1.0f + LOGD - l.w;
            }
        }
    }

    // ---- KL block reduction + one atomic per block ----
    float wk = wave_red_sum(klacc);
    __syncthreads();
    if ((tid & 63) == 0) kred[tid >> 6] = wk;
    __syncthreads();
    if (tid == 0) {
        float tot = 0.0f;
#pragma unroll
        for (int w = 0; w < NWAVE; ++w) tot += kred[w];
        atomicAdd(kl, 0.5f * tot);
    }
}

extern "C" void kernel_launch(void* const* d_in, const int* in_sizes, int n_in,
                              void* d_out, int out_size, void* d_ws, size_t ws_size,
                              hipStream_t stream) {
    const float* mu_q = (const float*)d_in[0];  // [K,T,V]
    const float* lsq  = (const float*)d_in[1];  // [K,T,V]
    const float* eps  = (const float*)d_in[2];  // [T,K,V]
    float* out = (float*)d_out;                 // [T,K,V] softmax, then 1 float KL
    float* kl  = out + (size_t)TDIM * KDIM * VDIM;

    // zero the KL accumulator each launch (graph-capture-safe)
    (void)hipMemsetAsync(kl, 0, sizeof(float), stream);

    dim3 grid(KDIM * NCHUNK);
    fused_beta_softmax_kl<<<grid, BLOCK, 0, stream>>>(mu_q, lsq, eps, out, kl);
}